// Round 2
// baseline (211.509 us; speedup 1.0000x reference)
//
#include <hip/hip_runtime.h>

#define B_ 8
#define S_ 32
#define N_ 512
#define E_ 8192
#define T_ 31

typedef __attribute__((ext_vector_type(8))) __bf16 bf16x8;
typedef __attribute__((ext_vector_type(4))) float f32x4;
typedef unsigned short u16;
typedef unsigned int u32;

__device__ __forceinline__ u16 f2b(float f) {
    union { float f; u32 u; } v; v.f = f;
    u32 r = v.u + 0x7FFF + ((v.u >> 16) & 1);
    return (u16)(r >> 16);
}

__device__ __forceinline__ f32x4 mfma16(bf16x8 a, bf16x8 b, f32x4 c) {
    return __builtin_amdgcn_mfma_f32_16x16x32_bf16(a, b, c, 0, 0, 0);
}

// ---------------- adjacency: degree ----------------
__global__ void deg_k(const int* __restrict__ ei, const float* __restrict__ ew,
                      float* __restrict__ deg) {
    int e = blockIdx.x * 256 + threadIdx.x;
    if (e >= E_ + N_) return;
    int col; float w;
    if (e < E_) { col = ei[E_ + e]; w = ew[e]; }
    else        { col = e - E_;     w = 1.f;  }
    atomicAdd(deg + col, w);
}

// ---------------- dis + coefficient collapse (merged) ----------------
__global__ void dis_coef_k(const float* __restrict__ deg, float* __restrict__ dis,
                           const float* __restrict__ start_w, const float* __restrict__ start_b,
                           const float* __restrict__ filt_w, const float* __restrict__ filt_b,
                           const float* __restrict__ gate_w, const float* __restrict__ gate_b,
                           const float* __restrict__ gcn_w, float* __restrict__ coef) {
    if (blockIdx.x < 2) {
        int n = blockIdx.x * 256 + threadIdx.x;
        float d = deg[n];
        dis[n] = (d > 0.f) ? rsqrtf(d) : 0.f;
        return;
    }
    __shared__ float W[16384];               // filt (8K) + gate (8K) staged coalesced
    __shared__ float sw[64], sb[64], A0[64], A1[64], C0[64];
    const int tid = threadIdx.x;
    if (tid < 64) { sw[tid] = start_w[tid]; sb[tid] = start_b[tid]; }
#pragma unroll
    for (int k = 0; k < 32; ++k) W[tid + k * 256] = filt_w[tid + k * 256];
#pragma unroll
    for (int k = 0; k < 32; ++k) W[8192 + tid + k * 256] = gate_w[tid + k * 256];
    __syncthreads();
    if (tid < 128) {
        const int o = tid & 63;
        const float* Wb = W + ((tid >= 64) ? 8192 : 0);
        float a0 = 0, a1 = 0, c = 0;
        for (int rr = 0; rr < 64; ++rr) {
            int r = (rr + o) & 63;          // skew to spread LDS banks
            float f0 = Wb[(o * 64 + r) * 2], f1 = Wb[(o * 64 + r) * 2 + 1];
            a0 += f0 * sw[r]; a1 += f1 * sw[r]; c += (f0 + f1) * sb[r];
        }
        if (tid < 64) { A0[o] = a0; A1[o] = a1; C0[o] = c + filt_b[o]; }
        else { coef[192 + o] = a0; coef[256 + o] = a1; coef[320 + o] = c + gate_b[o]; }
    }
    __syncthreads();
#pragma unroll
    for (int k = 0; k < 16; ++k) W[tid + k * 256] = gcn_w[tid + k * 256];
    __syncthreads();
    if (tid < 64) {
        const int o = tid;
        float u0 = 0, u1 = 0, u2 = 0;
        for (int dd = 0; dd < 64; ++dd) {
            int d = (dd + o) & 63;
            float g = W[o * 64 + d];
            u0 += g * A0[d]; u1 += g * A1[d]; u2 += g * C0[d];
        }
        coef[o] = u0; coef[64 + o] = u1; coef[128 + o] = u2;
    }
}

// ---------------- scatter (S + rowsum) + weight conversion (merged) ----------------
// W1[s][o], W2[e][s] XOR-swizzled bf16. W3[p][k'] bf16 with k'-permutation matched
// to the GEMM2 C-fragment layout: e = (k'&~31) | (lh*4 + (j&3) + 16*(j>>2)).
__global__ void scat_wconv_k(const int* __restrict__ ei, const float* __restrict__ ew,
                             const float* __restrict__ dis,
                             const float* __restrict__ skip_w, const float* __restrict__ end1_w,
                             const float* __restrict__ end2_w,
                             u16* __restrict__ W1, u16* __restrict__ W2, u16* __restrict__ W3,
                             float* __restrict__ S, float* __restrict__ rs) {
    const int bid = blockIdx.x;
    if (bid < 512) {
        int i = bid * 256 + threadIdx.x;
        if (i < 16384) { int s = i >> 6, o = i & 63; W1[(s << 6) | (o ^ ((s & 7) << 3))] = f2b(skip_w[i]); }
        { int e = i >> 8, s = i & 255; W2[(e << 8) | (s ^ ((e & 7) << 3))] = f2b(end1_w[i]); }
        if (i < 8192) {
            int p = i >> 9, k = i & 511;
            int eix = (k & 0x1E0) | (((k >> 3) & 3) << 2) | (k & 3) | (((k >> 2) & 1) << 4);
            float v = (p < 12) ? end2_w[(p << 9) + eix] : 0.f;
            W3[(p << 9) | k] = f2b(v);
        }
        return;
    }
    int e = (bid - 512) * 256 + threadIdx.x;
    if (e >= E_ + N_) return;
    int row, col; float w;
    if (e < E_) { row = ei[e]; col = ei[E_ + e]; w = ew[e]; }
    else        { row = col = e - E_;            w = 1.f;  }
    float nv = dis[row] * w * dis[col];
    atomicAdd(S + row * N_ + col, nv);        // S[src*N+tgt] = A_hat[tgt,src]
    atomicAdd(rs + col, nv);                  // rs[tgt] = row-sum of A_hat
}

// ---------------- Y[bt,m] = sum_n S[n*N+m]*x[bt,n] ----------------
__global__ void y_k(const float* __restrict__ x, const float* __restrict__ S,
                    float* __restrict__ Y) {
    __shared__ float xs[4][512];
    const int tid = threadIdx.x;
    const int m = blockIdx.x * 256 + tid;
    const int bt0 = blockIdx.y * 4;
#pragma unroll
    for (int i = 0; i < 8; ++i) {
        int idx = tid + i * 256;
        xs[idx >> 9][idx & 511] = x[(bt0 + (idx >> 9)) * 512 + (idx & 511)];
    }
    __syncthreads();
    float a0 = 0, a1 = 0, a2 = 0, a3 = 0;
#pragma unroll 4
    for (int n = 0; n < 512; ++n) {
        float sv = S[n * 512 + m];
        a0 += xs[0][n] * sv; a1 += xs[1][n] * sv;
        a2 += xs[2][n] * sv; a3 += xs[3][n] * sv;
    }
    Y[(bt0 + 0) * 512 + m] = a0; Y[(bt0 + 1) * 512 + m] = a1;
    Y[(bt0 + 2) * 512 + m] = a2; Y[(bt0 + 3) * 512 + m] = a3;
}

// ---------------- fused hg -> skip -> end1 -> end2 (E1 kept in registers) ----------------
__launch_bounds__(256, 3)
__global__ void fused_k(const float* __restrict__ x, const float* __restrict__ Y,
                        const float* __restrict__ rs, const float* __restrict__ coef,
                        const float* __restrict__ gcn_b, const float* __restrict__ skip_b,
                        const float* __restrict__ end1_b,
                        const u16* __restrict__ W1, const u16* __restrict__ W2,
                        const u16* __restrict__ W3, float* __restrict__ part) {
    __shared__ __align__(16) u16 HG[64 * 64];    // [pix][o]   swizzled  (8 KB)
    __shared__ __align__(16) u16 SK[64 * 256];   // [pix][s]   swizzled  (32 KB; reused f32 for OUT partials)
    __shared__ float xs0[64], xs1[64], ys0[64], ys1[64], rsl[64];
    __shared__ float cf[384], gb[64], bsk[256], be1[512];

    const int tid = threadIdx.x;
    const int wid = tid >> 6;
    const int lane = tid & 63;
    const int lr = lane & 15;
    const int lh = lane >> 4;

    const int bid = blockIdx.x;
    const int ntile = bid & 7;
    const int btix = bid >> 3;       // b*31 + t
    const int t = btix % 31;
    const int b = btix / 31;
    const int n0 = ntile * 64;
    const int bt = b * 32 + t;

    if (tid < 64) {
        xs0[tid] = x[bt * 512 + n0 + tid];
        xs1[tid] = x[(bt + 1) * 512 + n0 + tid];
        ys0[tid] = Y[bt * 512 + n0 + tid];
        ys1[tid] = Y[(bt + 1) * 512 + n0 + tid];
        rsl[tid] = rs[n0 + tid];
        gb[tid]  = gcn_b[tid];
    }
    cf[tid] = coef[tid];
    if (tid < 128) cf[256 + tid] = coef[256 + tid];
    bsk[tid] = skip_b[tid];
    be1[tid] = end1_b[tid];
    be1[tid + 256] = end1_b[tid + 256];
    __syncthreads();

    // phase A: hg = tanh(fg) * sigmoid(g)
#pragma unroll
    for (int k = 0; k < 16; ++k) {
        const int v = tid + k * 256;
        const int pix = v >> 6;
        const int o = v & 63;
        const float fgv = cf[o] * ys0[pix] + cf[64 + o] * ys1[pix]
                        + cf[128 + o] * rsl[pix] + gb[o];
        const float ggv = cf[192 + o] * xs0[pix] + cf[256 + o] * xs1[pix] + cf[320 + o];
        const float hv = tanhf(fgv) / (1.f + __expf(-ggv));
        HG[(pix << 6) | (o ^ ((pix & 7) << 3))] = f2b(hv);
    }
    __syncthreads();

    // GEMM1 (transposed): SKIP^T = skip_w x HG^T.  A=W1[s][o] (global), B=HG[pix][o] (LDS)
    {
        const int s0 = wid * 64;
        f32x4 acc[4][4];
#pragma unroll
        for (int i = 0; i < 4; ++i)
#pragma unroll
            for (int j = 0; j < 4; ++j) acc[i][j] = (f32x4){0.f, 0.f, 0.f, 0.f};
#pragma unroll
        for (int kk = 0; kk < 64; kk += 32) {
            const int kb = kk + lh * 8;
            bf16x8 a[4], bv[4];
#pragma unroll
            for (int i = 0; i < 4; ++i) {
                const int sr = s0 + i * 16 + lr;
                a[i] = *(const bf16x8*)(W1 + (sr << 6) + (kb ^ ((sr & 7) << 3)));
                const int pr = i * 16 + lr;
                bv[i] = *(const bf16x8*)(HG + (pr << 6) + (kb ^ ((pr & 7) << 3)));
            }
#pragma unroll
            for (int i = 0; i < 4; ++i)
#pragma unroll
                for (int j = 0; j < 4; ++j)
                    acc[i][j] = mfma16(a[i], bv[j], acc[i][j]);
        }
#pragma unroll
        for (int i = 0; i < 4; ++i) {
#pragma unroll
            for (int j = 0; j < 4; ++j) {
                const int pix = j * 16 + lr;
                const int xw = (pix & 7) << 3;
#pragma unroll
                for (int r = 0; r < 4; r += 2) {
                    const int s = s0 + i * 16 + lh * 4 + r;
                    const float v0 = fmaxf(acc[i][j][r] + bsk[s], 0.f);
                    const float v1 = fmaxf(acc[i][j][r + 1] + bsk[s + 1], 0.f);
                    *(u32*)(SK + (pix << 8) + (s ^ xw)) = (u32)f2b(v0) | ((u32)f2b(v1) << 16);
                }
            }
        }
    }
    __syncthreads();

    // GEMM2 (transposed): E1^T = end1_w x SKIP^T.  A=W2[e][s] (global), B=SK[pix][s] (LDS)
    // then GEMM3 fused in-register: OUT^T[pix][p] += E1^T[pix][e] * W3^T[e][p]
    {
        const int e0 = wid * 128;
        f32x4 acc[8][4];
#pragma unroll
        for (int i = 0; i < 8; ++i)
#pragma unroll
            for (int j = 0; j < 4; ++j) acc[i][j] = (f32x4){0.f, 0.f, 0.f, 0.f};
#pragma unroll
        for (int kk = 0; kk < 256; kk += 32) {
            const int kb = kk + lh * 8;
            bf16x8 a[8], bv[4];
#pragma unroll
            for (int i = 0; i < 8; ++i) {
                const int er = e0 + i * 16 + lr;
                a[i] = *(const bf16x8*)(W2 + (er << 8) + (kb ^ ((er & 7) << 3)));
            }
#pragma unroll
            for (int j = 0; j < 4; ++j) {
                const int pr = j * 16 + lr;
                bv[j] = *(const bf16x8*)(SK + (pr << 8) + (kb ^ ((pr & 7) << 3)));
            }
#pragma unroll
            for (int i = 0; i < 8; ++i)
#pragma unroll
                for (int j = 0; j < 4; ++j)
                    acc[i][j] = mfma16(a[i], bv[j], acc[i][j]);
        }
        __syncthreads();   // all waves done reading SK; safe to reuse as f32 scratch

        // bias + relu + pack to bf16 pairs (E1 values stay in registers)
        u32 pk[8][4][2];
#pragma unroll
        for (int i = 0; i < 8; ++i) {
#pragma unroll
            for (int j = 0; j < 4; ++j) {
                const int eb = e0 + i * 16 + lh * 4;
                const float v0 = fmaxf(acc[i][j][0] + be1[eb + 0], 0.f);
                const float v1 = fmaxf(acc[i][j][1] + be1[eb + 1], 0.f);
                const float v2 = fmaxf(acc[i][j][2] + be1[eb + 2], 0.f);
                const float v3 = fmaxf(acc[i][j][3] + be1[eb + 3], 0.f);
                pk[i][j][0] = (u32)f2b(v0) | ((u32)f2b(v1) << 16);
                pk[i][j][1] = (u32)f2b(v2) | ((u32)f2b(v3) << 16);
            }
        }
        // W3 B-fragments: col=p=lr, k'=lh*8+j, this wave's k'-range = [wid*128, wid*128+128)
        bf16x8 bfr[4];
#pragma unroll
        for (int c = 0; c < 4; ++c)
            bfr[c] = *(const bf16x8*)(W3 + (lr << 9) + e0 + c * 32 + lh * 8);
        f32x4 acc_out[4];
#pragma unroll
        for (int j = 0; j < 4; ++j) acc_out[j] = (f32x4){0.f, 0.f, 0.f, 0.f};
#pragma unroll
        for (int j = 0; j < 4; ++j) {
#pragma unroll
            for (int c = 0; c < 4; ++c) {
                union { u32 w[4]; bf16x8 v; } af;
                af.w[0] = pk[2 * c][j][0];
                af.w[1] = pk[2 * c][j][1];
                af.w[2] = pk[2 * c + 1][j][0];
                af.w[3] = pk[2 * c + 1][j][1];
                acc_out[j] = mfma16(af.v, bfr[c], acc_out[j]);
            }
        }
        // stage per-wave K-split partials: SKf[wid][pix][p]
        float* SKf = (float*)SK;
#pragma unroll
        for (int j = 0; j < 4; ++j)
#pragma unroll
            for (int r = 0; r < 4; ++r)
                SKf[wid * 1024 + (j * 16 + lh * 4 + r) * 16 + lr] = acc_out[j][r];
    }
    __syncthreads();

    // cross-wave reduce + write part
    {
        const f32x4* Sv = (const f32x4*)SK;
        f32x4 sum = Sv[tid] + Sv[256 + tid] + Sv[512 + tid] + Sv[768 + tid];
        const int pix = tid >> 2;
        const int p0 = (tid & 3) << 2;
        if (p0 < 12) {
#pragma unroll
            for (int r = 0; r < 4; ++r)
                part[(btix * 12 + p0 + r) * 512 + n0 + pix] = sum[r];
        }
    }
}

// ---------------- mean over t + end2 bias ----------------
__global__ void reduce_k(const float* __restrict__ part, const float* __restrict__ end2_b,
                         float* __restrict__ out) {
    int i = blockIdx.x * 256 + threadIdx.x;
    if (i >= 8 * 12 * 512) return;
    int n = i & 511;
    int p = (i >> 9) % 12;
    int b = i / (12 * 512);
    const float* src = part + ((b * 31) * 12 + p) * 512 + n;
    float s = 0.f;
#pragma unroll
    for (int t = 0; t < 31; ++t) s += src[t * 12 * 512];
    out[i] = s * (1.f / 31.f) + end2_b[p];
}

extern "C" void kernel_launch(void* const* d_in, const int* in_sizes, int n_in,
                              void* d_out, int out_size, void* d_ws, size_t ws_size,
                              hipStream_t stream) {
    const float* x       = (const float*)d_in[0];
    const int*   ei      = (const int*)  d_in[1];
    const float* ew      = (const float*)d_in[2];
    const float* start_w = (const float*)d_in[3];
    const float* start_b = (const float*)d_in[4];
    const float* filt_w  = (const float*)d_in[5];
    const float* filt_b  = (const float*)d_in[6];
    const float* gate_w  = (const float*)d_in[7];
    const float* gate_b  = (const float*)d_in[8];
    const float* gcn_w   = (const float*)d_in[9];
    const float* gcn_b   = (const float*)d_in[10];
    const float* skip_w  = (const float*)d_in[13];
    const float* skip_b  = (const float*)d_in[14];
    const float* end1_w  = (const float*)d_in[15];
    const float* end1_b  = (const float*)d_in[16];
    const float* end2_w  = (const float*)d_in[17];
    const float* end2_b  = (const float*)d_in[18];
    float* out = (float*)d_out;

    char* ws = (char*)d_ws;
    float* S    = (float*)(ws);                 // 1,048,576 B
    float* deg  = (float*)(ws + 1048576);       // 2048 B
    float* rs   = (float*)(ws + 1050624);       // 2048 B   (memset with S+deg)
    float* dis  = (float*)(ws + 1052672);       // 2048 B
    float* Y    = (float*)(ws + 1054720);       // 524,288 B
    float* coef = (float*)(ws + 1579008);       // 1536 B
    u16*   W1   = (u16*)  (ws + 1580544);       // 32,768 B
    u16*   W2   = (u16*)  (ws + 1613312);       // 262,144 B
    u16*   W3   = (u16*)  (ws + 1875456);       // 16,384 B
    float* part = (float*)(ws + 1891840);       // 6,094,848 B

    hipMemsetAsync(S, 0, 1048576 + 4096, stream);    // S + deg + rs
    hipLaunchKernelGGL(deg_k,      dim3(34),  dim3(256), 0, stream, ei, ew, deg);
    hipLaunchKernelGGL(dis_coef_k, dim3(3),   dim3(256), 0, stream, deg, dis,
                       start_w, start_b, filt_w, filt_b, gate_w, gate_b, gcn_w, coef);
    hipLaunchKernelGGL(scat_wconv_k, dim3(546), dim3(256), 0, stream, ei, ew, dis,
                       skip_w, end1_w, end2_w, W1, W2, W3, S, rs);
    hipLaunchKernelGGL(y_k,    dim3(2, 64), dim3(256), 0, stream, x, S, Y);
    hipLaunchKernelGGL(fused_k, dim3(1984), dim3(256), 0, stream,
                       x, Y, rs, coef, gcn_b, skip_b, end1_b, W1, W2, W3, part);
    hipLaunchKernelGGL(reduce_k, dim3(192), dim3(256), 0, stream, part, end2_b, out);
}

// Round 3
// 179.240 us; speedup vs baseline: 1.1800x; 1.1800x over previous
//
#include <hip/hip_runtime.h>

#define B_ 8
#define S_ 32
#define N_ 512
#define E_ 8192
#define T_ 31

typedef __attribute__((ext_vector_type(8))) __bf16 bf16x8;
typedef __attribute__((ext_vector_type(4))) float f32x4;
typedef unsigned short u16;
typedef unsigned int u32;

__device__ __forceinline__ u16 f2b(float f) {
    union { float f; u32 u; } v; v.f = f;
    u32 r = v.u + 0x7FFF + ((v.u >> 16) & 1);
    return (u16)(r >> 16);
}

__device__ __forceinline__ f32x4 mfma16(bf16x8 a, bf16x8 b, f32x4 c) {
    return __builtin_amdgcn_mfma_f32_16x16x32_bf16(a, b, c, 0, 0, 0);
}

// ---------------- adjacency: degree ----------------
__global__ void deg_k(const int* __restrict__ ei, const float* __restrict__ ew,
                      float* __restrict__ deg) {
    int e = blockIdx.x * 256 + threadIdx.x;
    if (e >= E_ + N_) return;
    int col; float w;
    if (e < E_) { col = ei[E_ + e]; w = ew[e]; }
    else        { col = e - E_;     w = 1.f;  }
    atomicAdd(deg + col, w);
}

// ---------------- dis + coefficient collapse (merged) ----------------
__global__ void dis_coef_k(const float* __restrict__ deg, float* __restrict__ dis,
                           const float* __restrict__ start_w, const float* __restrict__ start_b,
                           const float* __restrict__ filt_w, const float* __restrict__ filt_b,
                           const float* __restrict__ gate_w, const float* __restrict__ gate_b,
                           const float* __restrict__ gcn_w, float* __restrict__ coef) {
    if (blockIdx.x < 2) {
        int n = blockIdx.x * 256 + threadIdx.x;
        float d = deg[n];
        dis[n] = (d > 0.f) ? rsqrtf(d) : 0.f;
        return;
    }
    __shared__ float W[16384];               // filt (8K) + gate (8K) staged coalesced
    __shared__ float sw[64], sb[64], A0[64], A1[64], C0[64];
    const int tid = threadIdx.x;
    if (tid < 64) { sw[tid] = start_w[tid]; sb[tid] = start_b[tid]; }
#pragma unroll
    for (int k = 0; k < 32; ++k) W[tid + k * 256] = filt_w[tid + k * 256];
#pragma unroll
    for (int k = 0; k < 32; ++k) W[8192 + tid + k * 256] = gate_w[tid + k * 256];
    __syncthreads();
    if (tid < 128) {
        const int o = tid & 63;
        const float* Wb = W + ((tid >= 64) ? 8192 : 0);
        float a0 = 0, a1 = 0, c = 0;
        for (int rr = 0; rr < 64; ++rr) {
            int r = (rr + o) & 63;          // skew to spread LDS banks
            float f0 = Wb[(o * 64 + r) * 2], f1 = Wb[(o * 64 + r) * 2 + 1];
            a0 += f0 * sw[r]; a1 += f1 * sw[r]; c += (f0 + f1) * sb[r];
        }
        if (tid < 64) { A0[o] = a0; A1[o] = a1; C0[o] = c + filt_b[o]; }
        else { coef[192 + o] = a0; coef[256 + o] = a1; coef[320 + o] = c + gate_b[o]; }
    }
    __syncthreads();
#pragma unroll
    for (int k = 0; k < 16; ++k) W[tid + k * 256] = gcn_w[tid + k * 256];
    __syncthreads();
    if (tid < 64) {
        const int o = tid;
        float u0 = 0, u1 = 0, u2 = 0;
        for (int dd = 0; dd < 64; ++dd) {
            int d = (dd + o) & 63;
            float g = W[o * 64 + d];
            u0 += g * A0[d]; u1 += g * A1[d]; u2 += g * C0[d];
        }
        coef[o] = u0; coef[64 + o] = u1; coef[128 + o] = u2;
    }
}

// ---------------- scatter (S + rowsum) + weight conversion (merged) ----------------
// W1[s][o], W2[e][s] XOR-swizzled bf16. W3[p][k'] bf16 with k'-permutation matched
// to the GEMM2 C-fragment layout: e = (k'&~31) | (lh*4 + (j&3) + 16*(j>>2)).
__global__ void scat_wconv_k(const int* __restrict__ ei, const float* __restrict__ ew,
                             const float* __restrict__ dis,
                             const float* __restrict__ skip_w, const float* __restrict__ end1_w,
                             const float* __restrict__ end2_w,
                             u16* __restrict__ W1, u16* __restrict__ W2, u16* __restrict__ W3,
                             float* __restrict__ S, float* __restrict__ rs) {
    const int bid = blockIdx.x;
    if (bid < 512) {
        int i = bid * 256 + threadIdx.x;
        if (i < 16384) { int s = i >> 6, o = i & 63; W1[(s << 6) | (o ^ ((s & 7) << 3))] = f2b(skip_w[i]); }
        { int e = i >> 8, s = i & 255; W2[(e << 8) | (s ^ ((e & 7) << 3))] = f2b(end1_w[i]); }
        if (i < 8192) {
            int p = i >> 9, k = i & 511;
            int eix = (k & 0x1E0) | (((k >> 3) & 3) << 2) | (k & 3) | (((k >> 2) & 1) << 4);
            float v = (p < 12) ? end2_w[(p << 9) + eix] : 0.f;
            W3[(p << 9) | k] = f2b(v);
        }
        return;
    }
    int e = (bid - 512) * 256 + threadIdx.x;
    if (e >= E_ + N_) return;
    int row, col; float w;
    if (e < E_) { row = ei[e]; col = ei[E_ + e]; w = ew[e]; }
    else        { row = col = e - E_;            w = 1.f;  }
    float nv = dis[row] * w * dis[col];
    atomicAdd(S + row * N_ + col, nv);        // S[src*N+tgt] = A_hat[tgt,src]
    atomicAdd(rs + col, nv);                  // rs[tgt] = row-sum of A_hat
}

// ---------------- Y[bt,m] = sum_n S[n*N+m]*x[bt,n] ----------------
__global__ void y_k(const float* __restrict__ x, const float* __restrict__ S,
                    float* __restrict__ Y) {
    __shared__ float xs[4][512];
    const int tid = threadIdx.x;
    const int m = blockIdx.x * 256 + tid;
    const int bt0 = blockIdx.y * 4;
#pragma unroll
    for (int i = 0; i < 8; ++i) {
        int idx = tid + i * 256;
        xs[idx >> 9][idx & 511] = x[(bt0 + (idx >> 9)) * 512 + (idx & 511)];
    }
    __syncthreads();
    float a0 = 0, a1 = 0, a2 = 0, a3 = 0;
#pragma unroll 4
    for (int n = 0; n < 512; ++n) {
        float sv = S[n * 512 + m];
        a0 += xs[0][n] * sv; a1 += xs[1][n] * sv;
        a2 += xs[2][n] * sv; a3 += xs[3][n] * sv;
    }
    Y[(bt0 + 0) * 512 + m] = a0; Y[(bt0 + 1) * 512 + m] = a1;
    Y[(bt0 + 2) * 512 + m] = a2; Y[(bt0 + 3) * 512 + m] = a3;
}

// ---------------- fused hg -> skip -> end1 -> end2 (E1 in registers, 2 e-passes) ----------------
__launch_bounds__(256, 3)
__global__ void fused_k(const float* __restrict__ x, const float* __restrict__ Y,
                        const float* __restrict__ rs, const float* __restrict__ coef,
                        const float* __restrict__ gcn_b, const float* __restrict__ skip_b,
                        const float* __restrict__ end1_b,
                        const u16* __restrict__ W1, const u16* __restrict__ W2,
                        const u16* __restrict__ W3, float* __restrict__ part) {
    __shared__ __align__(16) u16 HG[64 * 64];    // [pix][o]   swizzled  (8 KB)
    __shared__ __align__(16) u16 SK[64 * 256];   // [pix][s]   swizzled  (32 KB; reused f32 for OUT partials)
    __shared__ float xs0[64], xs1[64], ys0[64], ys1[64], rsl[64];
    __shared__ float cf[384], gb[64], bsk[256], be1[512];

    const int tid = threadIdx.x;
    const int wid = tid >> 6;
    const int lane = tid & 63;
    const int lr = lane & 15;
    const int lh = lane >> 4;

    const int bid = blockIdx.x;
    const int ntile = bid & 7;
    const int btix = bid >> 3;       // b*31 + t
    const int t = btix % 31;
    const int b = btix / 31;
    const int n0 = ntile * 64;
    const int bt = b * 32 + t;

    if (tid < 64) {
        xs0[tid] = x[bt * 512 + n0 + tid];
        xs1[tid] = x[(bt + 1) * 512 + n0 + tid];
        ys0[tid] = Y[bt * 512 + n0 + tid];
        ys1[tid] = Y[(bt + 1) * 512 + n0 + tid];
        rsl[tid] = rs[n0 + tid];
        gb[tid]  = gcn_b[tid];
    }
    cf[tid] = coef[tid];
    if (tid < 128) cf[256 + tid] = coef[256 + tid];
    bsk[tid] = skip_b[tid];
    be1[tid] = end1_b[tid];
    be1[tid + 256] = end1_b[tid + 256];
    __syncthreads();

    // phase A: hg = tanh(fg) * sigmoid(g)  — fused: (e2f-1)*eg / ((e2f+1)*(1+eg))
#pragma unroll
    for (int k = 0; k < 16; ++k) {
        const int v = tid + k * 256;
        const int pix = v >> 6;
        const int o = v & 63;
        const float fgv = cf[o] * ys0[pix] + cf[64 + o] * ys1[pix]
                        + cf[128 + o] * rsl[pix] + gb[o];
        const float ggv = cf[192 + o] * xs0[pix] + cf[256 + o] * xs1[pix] + cf[320 + o];
        const float e2f = __expf(2.f * fgv);
        const float eg  = __expf(ggv);
        const float hv = ((e2f - 1.f) * eg) / ((e2f + 1.f) * (1.f + eg));
        HG[(pix << 6) | (o ^ ((pix & 7) << 3))] = f2b(hv);
    }
    __syncthreads();

    // GEMM1 (transposed): SKIP^T = skip_w x HG^T.  A=W1[s][o] (global), B=HG[pix][o] (LDS)
    {
        const int s0 = wid * 64;
        f32x4 acc[4][4];
#pragma unroll
        for (int i = 0; i < 4; ++i)
#pragma unroll
            for (int j = 0; j < 4; ++j) acc[i][j] = (f32x4){0.f, 0.f, 0.f, 0.f};
#pragma unroll
        for (int kk = 0; kk < 64; kk += 32) {
            const int kb = kk + lh * 8;
            bf16x8 a[4], bv[4];
#pragma unroll
            for (int i = 0; i < 4; ++i) {
                const int sr = s0 + i * 16 + lr;
                a[i] = *(const bf16x8*)(W1 + (sr << 6) + (kb ^ ((sr & 7) << 3)));
                const int pr = i * 16 + lr;
                bv[i] = *(const bf16x8*)(HG + (pr << 6) + (kb ^ ((pr & 7) << 3)));
            }
#pragma unroll
            for (int i = 0; i < 4; ++i)
#pragma unroll
                for (int j = 0; j < 4; ++j)
                    acc[i][j] = mfma16(a[i], bv[j], acc[i][j]);
        }
#pragma unroll
        for (int i = 0; i < 4; ++i) {
#pragma unroll
            for (int j = 0; j < 4; ++j) {
                const int pix = j * 16 + lr;
                const int xw = (pix & 7) << 3;
#pragma unroll
                for (int r = 0; r < 4; r += 2) {
                    const int s = s0 + i * 16 + lh * 4 + r;
                    const float v0 = fmaxf(acc[i][j][r] + bsk[s], 0.f);
                    const float v1 = fmaxf(acc[i][j][r + 1] + bsk[s + 1], 0.f);
                    *(u32*)(SK + (pix << 8) + (s ^ xw)) = (u32)f2b(v0) | ((u32)f2b(v1) << 16);
                }
            }
        }
    }
    __syncthreads();

    // GEMM2 (transposed) + GEMM3 fused in-register, TWO e-passes of 64 rows each
    // (keeps live VGPRs ~140 so launch_bounds(256,3) doesn't spill).
    {
        const int e0 = wid * 128;
        f32x4 acc_out[4];
#pragma unroll
        for (int j = 0; j < 4; ++j) acc_out[j] = (f32x4){0.f, 0.f, 0.f, 0.f};

#pragma unroll
        for (int pass = 0; pass < 2; ++pass) {
            const int ep = e0 + pass * 64;
            f32x4 acc[4][4];
#pragma unroll
            for (int i = 0; i < 4; ++i)
#pragma unroll
                for (int j = 0; j < 4; ++j) acc[i][j] = (f32x4){0.f, 0.f, 0.f, 0.f};
#pragma unroll
            for (int kk = 0; kk < 256; kk += 32) {
                const int kb = kk + lh * 8;
                bf16x8 a[4], bv[4];
#pragma unroll
                for (int i = 0; i < 4; ++i) {
                    const int er = ep + i * 16 + lr;
                    a[i] = *(const bf16x8*)(W2 + (er << 8) + (kb ^ ((er & 7) << 3)));
                }
#pragma unroll
                for (int j = 0; j < 4; ++j) {
                    const int pr = j * 16 + lr;
                    bv[j] = *(const bf16x8*)(SK + (pr << 8) + (kb ^ ((pr & 7) << 3)));
                }
#pragma unroll
                for (int i = 0; i < 4; ++i)
#pragma unroll
                    for (int j = 0; j < 4; ++j)
                        acc[i][j] = mfma16(a[i], bv[j], acc[i][j]);
            }
            // bias + relu + pack to bf16 pairs (E1 values stay in registers)
            u32 pk[4][4][2];
#pragma unroll
            for (int i = 0; i < 4; ++i) {
#pragma unroll
                for (int j = 0; j < 4; ++j) {
                    const int eb = ep + i * 16 + lh * 4;
                    const float v0 = fmaxf(acc[i][j][0] + be1[eb + 0], 0.f);
                    const float v1 = fmaxf(acc[i][j][1] + be1[eb + 1], 0.f);
                    const float v2 = fmaxf(acc[i][j][2] + be1[eb + 2], 0.f);
                    const float v3 = fmaxf(acc[i][j][3] + be1[eb + 3], 0.f);
                    pk[i][j][0] = (u32)f2b(v0) | ((u32)f2b(v1) << 16);
                    pk[i][j][1] = (u32)f2b(v2) | ((u32)f2b(v3) << 16);
                }
            }
            // GEMM3 partial: W3 B-fragments for this pass's k'-range (64 wide = 2 chunks)
            bf16x8 bfr[2];
#pragma unroll
            for (int c = 0; c < 2; ++c)
                bfr[c] = *(const bf16x8*)(W3 + (lr << 9) + ep + c * 32 + lh * 8);
#pragma unroll
            for (int j = 0; j < 4; ++j) {
#pragma unroll
                for (int c = 0; c < 2; ++c) {
                    union { u32 w[4]; bf16x8 v; } af;
                    af.w[0] = pk[2 * c][j][0];
                    af.w[1] = pk[2 * c][j][1];
                    af.w[2] = pk[2 * c + 1][j][0];
                    af.w[3] = pk[2 * c + 1][j][1];
                    acc_out[j] = mfma16(af.v, bfr[c], acc_out[j]);
                }
            }
        }
        __syncthreads();   // all waves done reading SK (both passes); reuse as f32 scratch

        // stage per-wave K-split partials: SKf[wid][pix][p]
        float* SKf = (float*)SK;
#pragma unroll
        for (int j = 0; j < 4; ++j)
#pragma unroll
            for (int r = 0; r < 4; ++r)
                SKf[wid * 1024 + (j * 16 + lh * 4 + r) * 16 + lr] = acc_out[j][r];
    }
    __syncthreads();

    // cross-wave reduce + write part
    {
        const f32x4* Sv = (const f32x4*)SK;
        f32x4 sum = Sv[tid] + Sv[256 + tid] + Sv[512 + tid] + Sv[768 + tid];
        const int pix = tid >> 2;
        const int p0 = (tid & 3) << 2;
        if (p0 < 12) {
#pragma unroll
            for (int r = 0; r < 4; ++r)
                part[(btix * 12 + p0 + r) * 512 + n0 + pix] = sum[r];
        }
    }
}

// ---------------- mean over t + end2 bias ----------------
__global__ void reduce_k(const float* __restrict__ part, const float* __restrict__ end2_b,
                         float* __restrict__ out) {
    int i = blockIdx.x * 256 + threadIdx.x;
    if (i >= 8 * 12 * 512) return;
    int n = i & 511;
    int p = (i >> 9) % 12;
    int b = i / (12 * 512);
    const float* src = part + ((b * 31) * 12 + p) * 512 + n;
    float s = 0.f;
#pragma unroll
    for (int t = 0; t < 31; ++t) s += src[t * 12 * 512];
    out[i] = s * (1.f / 31.f) + end2_b[p];
}

extern "C" void kernel_launch(void* const* d_in, const int* in_sizes, int n_in,
                              void* d_out, int out_size, void* d_ws, size_t ws_size,
                              hipStream_t stream) {
    const float* x       = (const float*)d_in[0];
    const int*   ei      = (const int*)  d_in[1];
    const float* ew      = (const float*)d_in[2];
    const float* start_w = (const float*)d_in[3];
    const float* start_b = (const float*)d_in[4];
    const float* filt_w  = (const float*)d_in[5];
    const float* filt_b  = (const float*)d_in[6];
    const float* gate_w  = (const float*)d_in[7];
    const float* gate_b  = (const float*)d_in[8];
    const float* gcn_w   = (const float*)d_in[9];
    const float* gcn_b   = (const float*)d_in[10];
    const float* skip_w  = (const float*)d_in[13];
    const float* skip_b  = (const float*)d_in[14];
    const float* end1_w  = (const float*)d_in[15];
    const float* end1_b  = (const float*)d_in[16];
    const float* end2_w  = (const float*)d_in[17];
    const float* end2_b  = (const float*)d_in[18];
    float* out = (float*)d_out;

    char* ws = (char*)d_ws;
    float* S    = (float*)(ws);                 // 1,048,576 B
    float* deg  = (float*)(ws + 1048576);       // 2048 B
    float* rs   = (float*)(ws + 1050624);       // 2048 B   (memset with S+deg)
    float* dis  = (float*)(ws + 1052672);       // 2048 B
    float* Y    = (float*)(ws + 1054720);       // 524,288 B
    float* coef = (float*)(ws + 1579008);       // 1536 B
    u16*   W1   = (u16*)  (ws + 1580544);       // 32,768 B
    u16*   W2   = (u16*)  (ws + 1613312);       // 262,144 B
    u16*   W3   = (u16*)  (ws + 1875456);       // 16,384 B
    float* part = (float*)(ws + 1891840);       // 6,094,848 B

    hipMemsetAsync(S, 0, 1048576 + 4096, stream);    // S + deg + rs
    hipLaunchKernelGGL(deg_k,      dim3(34),  dim3(256), 0, stream, ei, ew, deg);
    hipLaunchKernelGGL(dis_coef_k, dim3(3),   dim3(256), 0, stream, deg, dis,
                       start_w, start_b, filt_w, filt_b, gate_w, gate_b, gcn_w, coef);
    hipLaunchKernelGGL(scat_wconv_k, dim3(546), dim3(256), 0, stream, ei, ew, dis,
                       skip_w, end1_w, end2_w, W1, W2, W3, S, rs);
    hipLaunchKernelGGL(y_k,    dim3(2, 64), dim3(256), 0, stream, x, S, Y);
    hipLaunchKernelGGL(fused_k, dim3(1984), dim3(256), 0, stream,
                       x, Y, rs, coef, gcn_b, skip_b, end1_b, W1, W2, W3, part);
    hipLaunchKernelGGL(reduce_k, dim3(192), dim3(256), 0, stream, part, end2_b, out);
}

// Round 4
// 159.547 us; speedup vs baseline: 1.3257x; 1.1234x over previous
//
#include <hip/hip_runtime.h>

#define B_ 8
#define S_ 32
#define N_ 512
#define E_ 8192
#define T_ 31

typedef __attribute__((ext_vector_type(8))) __bf16 bf16x8;
typedef __attribute__((ext_vector_type(4))) float f32x4;
typedef unsigned short u16;
typedef unsigned int u32;

__device__ __forceinline__ u16 f2b(float f) {
    union { float f; u32 u; } v; v.f = f;
    u32 r = v.u + 0x7FFF + ((v.u >> 16) & 1);
    return (u16)(r >> 16);
}

__device__ __forceinline__ f32x4 mfma16(bf16x8 a, bf16x8 b, f32x4 c) {
    return __builtin_amdgcn_mfma_f32_16x16x32_bf16(a, b, c, 0, 0, 0);
}

// ---------------- adjacency: degree ----------------
__global__ void deg_k(const int* __restrict__ ei, const float* __restrict__ ew,
                      float* __restrict__ deg) {
    int e = blockIdx.x * 256 + threadIdx.x;
    if (e >= E_ + N_) return;
    int col; float w;
    if (e < E_) { col = ei[E_ + e]; w = ew[e]; }
    else        { col = e - E_;     w = 1.f;  }
    atomicAdd(deg + col, w);
}

// ---------------- dis + coefficient collapse (merged) ----------------
__global__ void dis_coef_k(const float* __restrict__ deg, float* __restrict__ dis,
                           const float* __restrict__ start_w, const float* __restrict__ start_b,
                           const float* __restrict__ filt_w, const float* __restrict__ filt_b,
                           const float* __restrict__ gate_w, const float* __restrict__ gate_b,
                           const float* __restrict__ gcn_w, float* __restrict__ coef) {
    if (blockIdx.x < 2) {
        int n = blockIdx.x * 256 + threadIdx.x;
        float d = deg[n];
        dis[n] = (d > 0.f) ? rsqrtf(d) : 0.f;
        return;
    }
    __shared__ float W[16384];               // filt (8K) + gate (8K) staged coalesced
    __shared__ float sw[64], sb[64], A0[64], A1[64], C0[64];
    const int tid = threadIdx.x;
    if (tid < 64) { sw[tid] = start_w[tid]; sb[tid] = start_b[tid]; }
#pragma unroll
    for (int k = 0; k < 32; ++k) W[tid + k * 256] = filt_w[tid + k * 256];
#pragma unroll
    for (int k = 0; k < 32; ++k) W[8192 + tid + k * 256] = gate_w[tid + k * 256];
    __syncthreads();
    if (tid < 128) {
        const int o = tid & 63;
        const float* Wb = W + ((tid >= 64) ? 8192 : 0);
        float a0 = 0, a1 = 0, c = 0;
        for (int rr = 0; rr < 64; ++rr) {
            int r = (rr + o) & 63;          // skew to spread LDS banks
            float f0 = Wb[(o * 64 + r) * 2], f1 = Wb[(o * 64 + r) * 2 + 1];
            a0 += f0 * sw[r]; a1 += f1 * sw[r]; c += (f0 + f1) * sb[r];
        }
        if (tid < 64) { A0[o] = a0; A1[o] = a1; C0[o] = c + filt_b[o]; }
        else { coef[192 + o] = a0; coef[256 + o] = a1; coef[320 + o] = c + gate_b[o]; }
    }
    __syncthreads();
#pragma unroll
    for (int k = 0; k < 16; ++k) W[tid + k * 256] = gcn_w[tid + k * 256];
    __syncthreads();
    if (tid < 64) {
        const int o = tid;
        float u0 = 0, u1 = 0, u2 = 0;
        for (int dd = 0; dd < 64; ++dd) {
            int d = (dd + o) & 63;
            float g = W[o * 64 + d];
            u0 += g * A0[d]; u1 += g * A1[d]; u2 += g * C0[d];
        }
        coef[o] = u0; coef[64 + o] = u1; coef[128 + o] = u2;
    }
}

// ---------------- scatter (S + rowsum) + weight conversion (merged) ----------------
// W1[s][o], W2[e][s] XOR-swizzled bf16. W3[p][k'] bf16 with k'-permutation matched
// to the GEMM2 C-fragment layout: e = (k'&~31) | (lh*4 + (j&3) + 16*(j>>2)).
__global__ void scat_wconv_k(const int* __restrict__ ei, const float* __restrict__ ew,
                             const float* __restrict__ dis,
                             const float* __restrict__ skip_w, const float* __restrict__ end1_w,
                             const float* __restrict__ end2_w,
                             u16* __restrict__ W1, u16* __restrict__ W2, u16* __restrict__ W3,
                             float* __restrict__ S, float* __restrict__ rs) {
    const int bid = blockIdx.x;
    if (bid < 512) {
        int i = bid * 256 + threadIdx.x;
        if (i < 16384) { int s = i >> 6, o = i & 63; W1[(s << 6) | (o ^ ((s & 7) << 3))] = f2b(skip_w[i]); }
        { int e = i >> 8, s = i & 255; W2[(e << 8) | (s ^ ((e & 7) << 3))] = f2b(end1_w[i]); }
        if (i < 8192) {
            int p = i >> 9, k = i & 511;
            int eix = (k & 0x1E0) | (((k >> 3) & 3) << 2) | (k & 3) | (((k >> 2) & 1) << 4);
            float v = (p < 12) ? end2_w[(p << 9) + eix] : 0.f;
            W3[(p << 9) | k] = f2b(v);
        }
        return;
    }
    int e = (bid - 512) * 256 + threadIdx.x;
    if (e >= E_ + N_) return;
    int row, col; float w;
    if (e < E_) { row = ei[e]; col = ei[E_ + e]; w = ew[e]; }
    else        { row = col = e - E_;            w = 1.f;  }
    float nv = dis[row] * w * dis[col];
    atomicAdd(S + row * N_ + col, nv);        // S[src*N+tgt] = A_hat[tgt,src]
    atomicAdd(rs + col, nv);                  // rs[tgt] = row-sum of A_hat
}

// ---------------- Y[bt,m] = sum_n S[n*N+m]*x[bt,n] ----------------
__global__ void y_k(const float* __restrict__ x, const float* __restrict__ S,
                    float* __restrict__ Y) {
    __shared__ float xs[4][512];
    const int tid = threadIdx.x;
    const int m = blockIdx.x * 256 + tid;
    const int bt0 = blockIdx.y * 4;
#pragma unroll
    for (int i = 0; i < 8; ++i) {
        int idx = tid + i * 256;
        xs[idx >> 9][idx & 511] = x[(bt0 + (idx >> 9)) * 512 + (idx & 511)];
    }
    __syncthreads();
    float a0 = 0, a1 = 0, a2 = 0, a3 = 0;
#pragma unroll 4
    for (int n = 0; n < 512; ++n) {
        float sv = S[n * 512 + m];
        a0 += xs[0][n] * sv; a1 += xs[1][n] * sv;
        a2 += xs[2][n] * sv; a3 += xs[3][n] * sv;
    }
    Y[(bt0 + 0) * 512 + m] = a0; Y[(bt0 + 1) * 512 + m] = a1;
    Y[(bt0 + 2) * 512 + m] = a2; Y[(bt0 + 3) * 512 + m] = a3;
}

// ---------------- fused hg -> skip -> end1 -> end2 (E1 in registers, 2 e-passes) ----------------
// NOTE: launch_bounds(256,1) — the (256,3) variant made the backend cap arch
// VGPRs at 84 and spill ~330MB/dispatch to scratch (rounds 2-3). Natural
// allocation (~144) fits 3 waves/SIMD anyway; occupancy is LDS-limited (47KB
// -> 3 blocks/CU).
__launch_bounds__(256, 1)
__global__ void fused_k(const float* __restrict__ x, const float* __restrict__ Y,
                        const float* __restrict__ rs, const float* __restrict__ coef,
                        const float* __restrict__ gcn_b, const float* __restrict__ skip_b,
                        const float* __restrict__ end1_b,
                        const u16* __restrict__ W1, const u16* __restrict__ W2,
                        const u16* __restrict__ W3, float* __restrict__ part) {
    __shared__ __align__(16) u16 HG[64 * 64];    // [pix][o]   swizzled  (8 KB)
    __shared__ __align__(16) u16 SK[64 * 256];   // [pix][s]   swizzled  (32 KB; reused f32 for OUT partials)
    __shared__ float xs0[64], xs1[64], ys0[64], ys1[64], rsl[64];
    __shared__ float cf[384], gb[64], bsk[256], be1[512];

    const int tid = threadIdx.x;
    const int wid = tid >> 6;
    const int lane = tid & 63;
    const int lr = lane & 15;
    const int lh = lane >> 4;

    const int bid = blockIdx.x;
    const int ntile = bid & 7;
    const int btix = bid >> 3;       // b*31 + t
    const int t = btix % 31;
    const int b = btix / 31;
    const int n0 = ntile * 64;
    const int bt = b * 32 + t;

    if (tid < 64) {
        xs0[tid] = x[bt * 512 + n0 + tid];
        xs1[tid] = x[(bt + 1) * 512 + n0 + tid];
        ys0[tid] = Y[bt * 512 + n0 + tid];
        ys1[tid] = Y[(bt + 1) * 512 + n0 + tid];
        rsl[tid] = rs[n0 + tid];
        gb[tid]  = gcn_b[tid];
    }
    cf[tid] = coef[tid];
    if (tid < 128) cf[256 + tid] = coef[256 + tid];
    bsk[tid] = skip_b[tid];
    be1[tid] = end1_b[tid];
    be1[tid + 256] = end1_b[tid + 256];
    __syncthreads();

    // phase A: hg = tanh(fg) * sigmoid(g)  — fused: (e2f-1)*eg / ((e2f+1)*(1+eg))
#pragma unroll
    for (int k = 0; k < 16; ++k) {
        const int v = tid + k * 256;
        const int pix = v >> 6;
        const int o = v & 63;
        const float fgv = cf[o] * ys0[pix] + cf[64 + o] * ys1[pix]
                        + cf[128 + o] * rsl[pix] + gb[o];
        const float ggv = cf[192 + o] * xs0[pix] + cf[256 + o] * xs1[pix] + cf[320 + o];
        const float e2f = __expf(2.f * fgv);
        const float eg  = __expf(ggv);
        const float hv = ((e2f - 1.f) * eg) / ((e2f + 1.f) * (1.f + eg));
        HG[(pix << 6) | (o ^ ((pix & 7) << 3))] = f2b(hv);
    }
    __syncthreads();

    // GEMM1 (transposed): SKIP^T = skip_w x HG^T.  A=W1[s][o] (global), B=HG[pix][o] (LDS)
    {
        const int s0 = wid * 64;
        f32x4 acc[4][4];
#pragma unroll
        for (int i = 0; i < 4; ++i)
#pragma unroll
            for (int j = 0; j < 4; ++j) acc[i][j] = (f32x4){0.f, 0.f, 0.f, 0.f};
#pragma unroll
        for (int kk = 0; kk < 64; kk += 32) {
            const int kb = kk + lh * 8;
            bf16x8 a[4], bv[4];
#pragma unroll
            for (int i = 0; i < 4; ++i) {
                const int sr = s0 + i * 16 + lr;
                a[i] = *(const bf16x8*)(W1 + (sr << 6) + (kb ^ ((sr & 7) << 3)));
                const int pr = i * 16 + lr;
                bv[i] = *(const bf16x8*)(HG + (pr << 6) + (kb ^ ((pr & 7) << 3)));
            }
#pragma unroll
            for (int i = 0; i < 4; ++i)
#pragma unroll
                for (int j = 0; j < 4; ++j)
                    acc[i][j] = mfma16(a[i], bv[j], acc[i][j]);
        }
#pragma unroll
        for (int i = 0; i < 4; ++i) {
#pragma unroll
            for (int j = 0; j < 4; ++j) {
                const int pix = j * 16 + lr;
                const int xw = (pix & 7) << 3;
#pragma unroll
                for (int r = 0; r < 4; r += 2) {
                    const int s = s0 + i * 16 + lh * 4 + r;
                    const float v0 = fmaxf(acc[i][j][r] + bsk[s], 0.f);
                    const float v1 = fmaxf(acc[i][j][r + 1] + bsk[s + 1], 0.f);
                    *(u32*)(SK + (pix << 8) + (s ^ xw)) = (u32)f2b(v0) | ((u32)f2b(v1) << 16);
                }
            }
        }
    }
    __syncthreads();

    // GEMM2 (transposed) + GEMM3 fused in-register, TWO e-passes of 64 rows each.
    {
        const int e0 = wid * 128;
        f32x4 acc_out[4];
#pragma unroll
        for (int j = 0; j < 4; ++j) acc_out[j] = (f32x4){0.f, 0.f, 0.f, 0.f};

#pragma unroll
        for (int pass = 0; pass < 2; ++pass) {
            const int ep = e0 + pass * 64;
            f32x4 acc[4][4];
#pragma unroll
            for (int i = 0; i < 4; ++i)
#pragma unroll
                for (int j = 0; j < 4; ++j) acc[i][j] = (f32x4){0.f, 0.f, 0.f, 0.f};
#pragma unroll
            for (int kk = 0; kk < 256; kk += 32) {
                const int kb = kk + lh * 8;
                bf16x8 a[4], bv[4];
#pragma unroll
                for (int i = 0; i < 4; ++i) {
                    const int er = ep + i * 16 + lr;
                    a[i] = *(const bf16x8*)(W2 + (er << 8) + (kb ^ ((er & 7) << 3)));
                }
#pragma unroll
                for (int j = 0; j < 4; ++j) {
                    const int pr = j * 16 + lr;
                    bv[j] = *(const bf16x8*)(SK + (pr << 8) + (kb ^ ((pr & 7) << 3)));
                }
#pragma unroll
                for (int i = 0; i < 4; ++i)
#pragma unroll
                    for (int j = 0; j < 4; ++j)
                        acc[i][j] = mfma16(a[i], bv[j], acc[i][j]);
            }
            // bias + relu + pack to bf16 pairs (E1 values stay in registers)
            u32 pk[4][4][2];
#pragma unroll
            for (int i = 0; i < 4; ++i) {
#pragma unroll
                for (int j = 0; j < 4; ++j) {
                    const int eb = ep + i * 16 + lh * 4;
                    const float v0 = fmaxf(acc[i][j][0] + be1[eb + 0], 0.f);
                    const float v1 = fmaxf(acc[i][j][1] + be1[eb + 1], 0.f);
                    const float v2 = fmaxf(acc[i][j][2] + be1[eb + 2], 0.f);
                    const float v3 = fmaxf(acc[i][j][3] + be1[eb + 3], 0.f);
                    pk[i][j][0] = (u32)f2b(v0) | ((u32)f2b(v1) << 16);
                    pk[i][j][1] = (u32)f2b(v2) | ((u32)f2b(v3) << 16);
                }
            }
            // GEMM3 partial: W3 B-fragments for this pass's k'-range (64 wide = 2 chunks)
            bf16x8 bfr[2];
#pragma unroll
            for (int c = 0; c < 2; ++c)
                bfr[c] = *(const bf16x8*)(W3 + (lr << 9) + ep + c * 32 + lh * 8);
#pragma unroll
            for (int j = 0; j < 4; ++j) {
#pragma unroll
                for (int c = 0; c < 2; ++c) {
                    union { u32 w[4]; bf16x8 v; } af;
                    af.w[0] = pk[2 * c][j][0];
                    af.w[1] = pk[2 * c][j][1];
                    af.w[2] = pk[2 * c + 1][j][0];
                    af.w[3] = pk[2 * c + 1][j][1];
                    acc_out[j] = mfma16(af.v, bfr[c], acc_out[j]);
                }
            }
        }
        __syncthreads();   // all waves done reading SK (both passes); reuse as f32 scratch

        // stage per-wave K-split partials: SKf[wid][pix][p]
        float* SKf = (float*)SK;
#pragma unroll
        for (int j = 0; j < 4; ++j)
#pragma unroll
            for (int r = 0; r < 4; ++r)
                SKf[wid * 1024 + (j * 16 + lh * 4 + r) * 16 + lr] = acc_out[j][r];
    }
    __syncthreads();

    // cross-wave reduce + write part
    {
        const f32x4* Sv = (const f32x4*)SK;
        f32x4 sum = Sv[tid] + Sv[256 + tid] + Sv[512 + tid] + Sv[768 + tid];
        const int pix = tid >> 2;
        const int p0 = (tid & 3) << 2;
        if (p0 < 12) {
#pragma unroll
            for (int r = 0; r < 4; ++r)
                part[(btix * 12 + p0 + r) * 512 + n0 + pix] = sum[r];
        }
    }
}

// ---------------- mean over t + end2 bias ----------------
__global__ void reduce_k(const float* __restrict__ part, const float* __restrict__ end2_b,
                         float* __restrict__ out) {
    int i = blockIdx.x * 256 + threadIdx.x;
    if (i >= 8 * 12 * 512) return;
    int n = i & 511;
    int p = (i >> 9) % 12;
    int b = i / (12 * 512);
    const float* src = part + ((b * 31) * 12 + p) * 512 + n;
    float s = 0.f;
#pragma unroll
    for (int t = 0; t < 31; ++t) s += src[t * 12 * 512];
    out[i] = s * (1.f / 31.f) + end2_b[p];
}

extern "C" void kernel_launch(void* const* d_in, const int* in_sizes, int n_in,
                              void* d_out, int out_size, void* d_ws, size_t ws_size,
                              hipStream_t stream) {
    const float* x       = (const float*)d_in[0];
    const int*   ei      = (const int*)  d_in[1];
    const float* ew      = (const float*)d_in[2];
    const float* start_w = (const float*)d_in[3];
    const float* start_b = (const float*)d_in[4];
    const float* filt_w  = (const float*)d_in[5];
    const float* filt_b  = (const float*)d_in[6];
    const float* gate_w  = (const float*)d_in[7];
    const float* gate_b  = (const float*)d_in[8];
    const float* gcn_w   = (const float*)d_in[9];
    const float* gcn_b   = (const float*)d_in[10];
    const float* skip_w  = (const float*)d_in[13];
    const float* skip_b  = (const float*)d_in[14];
    const float* end1_w  = (const float*)d_in[15];
    const float* end1_b  = (const float*)d_in[16];
    const float* end2_w  = (const float*)d_in[17];
    const float* end2_b  = (const float*)d_in[18];
    float* out = (float*)d_out;

    char* ws = (char*)d_ws;
    float* S    = (float*)(ws);                 // 1,048,576 B
    float* deg  = (float*)(ws + 1048576);       // 2048 B
    float* rs   = (float*)(ws + 1050624);       // 2048 B   (memset with S+deg)
    float* dis  = (float*)(ws + 1052672);       // 2048 B
    float* Y    = (float*)(ws + 1054720);       // 524,288 B
    float* coef = (float*)(ws + 1579008);       // 1536 B
    u16*   W1   = (u16*)  (ws + 1580544);       // 32,768 B
    u16*   W2   = (u16*)  (ws + 1613312);       // 262,144 B
    u16*   W3   = (u16*)  (ws + 1875456);       // 16,384 B
    float* part = (float*)(ws + 1891840);       // 6,094,848 B

    hipMemsetAsync(S, 0, 1048576 + 4096, stream);    // S + deg + rs
    hipLaunchKernelGGL(deg_k,      dim3(34),  dim3(256), 0, stream, ei, ew, deg);
    hipLaunchKernelGGL(dis_coef_k, dim3(3),   dim3(256), 0, stream, deg, dis,
                       start_w, start_b, filt_w, filt_b, gate_w, gate_b, gcn_w, coef);
    hipLaunchKernelGGL(scat_wconv_k, dim3(546), dim3(256), 0, stream, ei, ew, dis,
                       skip_w, end1_w, end2_w, W1, W2, W3, S, rs);
    hipLaunchKernelGGL(y_k,    dim3(2, 64), dim3(256), 0, stream, x, S, Y);
    hipLaunchKernelGGL(fused_k, dim3(1984), dim3(256), 0, stream,
                       x, Y, rs, coef, gcn_b, skip_b, end1_b, W1, W2, W3, part);
    hipLaunchKernelGGL(reduce_k, dim3(192), dim3(256), 0, stream, part, end2_b, out);
}

// Round 5
// 126.323 us; speedup vs baseline: 1.6744x; 1.2630x over previous
//
#include <hip/hip_runtime.h>

#define B_ 8
#define S_ 32
#define N_ 512
#define E_ 8192
#define T_ 31

typedef __attribute__((ext_vector_type(8))) __bf16 bf16x8;
typedef __attribute__((ext_vector_type(4))) float f32x4;
typedef unsigned short u16;
typedef unsigned int u32;

__device__ __forceinline__ u16 f2b(float f) {
    union { float f; u32 u; } v; v.f = f;
    u32 r = v.u + 0x7FFF + ((v.u >> 16) & 1);
    return (u16)(r >> 16);
}

__device__ __forceinline__ f32x4 mfma16(bf16x8 a, bf16x8 b, f32x4 c) {
    return __builtin_amdgcn_mfma_f32_16x16x32_bf16(a, b, c, 0, 0, 0);
}

// ---------------- adjacency: degree ----------------
__global__ void deg_k(const int* __restrict__ ei, const float* __restrict__ ew,
                      float* __restrict__ deg) {
    int e = blockIdx.x * 256 + threadIdx.x;
    if (e >= E_ + N_) return;
    int col; float w;
    if (e < E_) { col = ei[E_ + e]; w = ew[e]; }
    else        { col = e - E_;     w = 1.f;  }
    atomicAdd(deg + col, w);
}

// ---------------- dis + coefficient collapse (merged) ----------------
__global__ void dis_coef_k(const float* __restrict__ deg, float* __restrict__ dis,
                           const float* __restrict__ start_w, const float* __restrict__ start_b,
                           const float* __restrict__ filt_w, const float* __restrict__ filt_b,
                           const float* __restrict__ gate_w, const float* __restrict__ gate_b,
                           const float* __restrict__ gcn_w, float* __restrict__ coef) {
    if (blockIdx.x < 2) {
        int n = blockIdx.x * 256 + threadIdx.x;
        float d = deg[n];
        dis[n] = (d > 0.f) ? rsqrtf(d) : 0.f;
        return;
    }
    __shared__ float W[16384];               // filt (8K) + gate (8K) staged coalesced
    __shared__ float sw[64], sb[64], A0[64], A1[64], C0[64];
    const int tid = threadIdx.x;
    if (tid < 64) { sw[tid] = start_w[tid]; sb[tid] = start_b[tid]; }
#pragma unroll
    for (int k = 0; k < 32; ++k) W[tid + k * 256] = filt_w[tid + k * 256];
#pragma unroll
    for (int k = 0; k < 32; ++k) W[8192 + tid + k * 256] = gate_w[tid + k * 256];
    __syncthreads();
    if (tid < 128) {
        const int o = tid & 63;
        const float* Wb = W + ((tid >= 64) ? 8192 : 0);
        float a0 = 0, a1 = 0, c = 0;
        for (int rr = 0; rr < 64; ++rr) {
            int r = (rr + o) & 63;          // skew to spread LDS banks
            float f0 = Wb[(o * 64 + r) * 2], f1 = Wb[(o * 64 + r) * 2 + 1];
            a0 += f0 * sw[r]; a1 += f1 * sw[r]; c += (f0 + f1) * sb[r];
        }
        if (tid < 64) { A0[o] = a0; A1[o] = a1; C0[o] = c + filt_b[o]; }
        else { coef[192 + o] = a0; coef[256 + o] = a1; coef[320 + o] = c + gate_b[o]; }
    }
    __syncthreads();
#pragma unroll
    for (int k = 0; k < 16; ++k) W[tid + k * 256] = gcn_w[tid + k * 256];
    __syncthreads();
    if (tid < 64) {
        const int o = tid;
        float u0 = 0, u1 = 0, u2 = 0;
        for (int dd = 0; dd < 64; ++dd) {
            int d = (dd + o) & 63;
            float g = W[o * 64 + d];
            u0 += g * A0[d]; u1 += g * A1[d]; u2 += g * C0[d];
        }
        coef[o] = u0; coef[64 + o] = u1; coef[128 + o] = u2;
    }
}

// ---------------- scatter (S + rowsum) + weight conversion (merged) ----------------
// W1[s][o], W2[e][s] XOR-swizzled bf16. W3[p][k'] bf16 with k'-permutation matched
// to the GEMM2 C-fragment layout: e = (k'&~31) | (lh*4 + (j&3) + 16*(j>>2)).
__global__ void scat_wconv_k(const int* __restrict__ ei, const float* __restrict__ ew,
                             const float* __restrict__ dis,
                             const float* __restrict__ skip_w, const float* __restrict__ end1_w,
                             const float* __restrict__ end2_w,
                             u16* __restrict__ W1, u16* __restrict__ W2, u16* __restrict__ W3,
                             float* __restrict__ S, float* __restrict__ rs) {
    const int bid = blockIdx.x;
    if (bid < 512) {
        int i = bid * 256 + threadIdx.x;
        if (i < 16384) { int s = i >> 6, o = i & 63; W1[(s << 6) | (o ^ ((s & 7) << 3))] = f2b(skip_w[i]); }
        { int e = i >> 8, s = i & 255; W2[(e << 8) | (s ^ ((e & 7) << 3))] = f2b(end1_w[i]); }
        if (i < 8192) {
            int p = i >> 9, k = i & 511;
            int eix = (k & 0x1E0) | (((k >> 3) & 3) << 2) | (k & 3) | (((k >> 2) & 1) << 4);
            float v = (p < 12) ? end2_w[(p << 9) + eix] : 0.f;
            W3[(p << 9) | k] = f2b(v);
        }
        return;
    }
    int e = (bid - 512) * 256 + threadIdx.x;
    if (e >= E_ + N_) return;
    int row, col; float w;
    if (e < E_) { row = ei[e]; col = ei[E_ + e]; w = ew[e]; }
    else        { row = col = e - E_;            w = 1.f;  }
    float nv = dis[row] * w * dis[col];
    atomicAdd(S + row * N_ + col, nv);        // S[src*N+tgt] = A_hat[tgt,src]
    atomicAdd(rs + col, nv);                  // rs[tgt] = row-sum of A_hat
}

// ---------------- Y[bt,m] = sum_n S[n*N+m]*x[bt,n] ----------------
__global__ void y_k(const float* __restrict__ x, const float* __restrict__ S,
                    float* __restrict__ Y) {
    __shared__ float xs[4][512];
    const int tid = threadIdx.x;
    const int m = blockIdx.x * 256 + tid;
    const int bt0 = blockIdx.y * 4;
#pragma unroll
    for (int i = 0; i < 8; ++i) {
        int idx = tid + i * 256;
        xs[idx >> 9][idx & 511] = x[(bt0 + (idx >> 9)) * 512 + (idx & 511)];
    }
    __syncthreads();
    float a0 = 0, a1 = 0, a2 = 0, a3 = 0;
#pragma unroll 4
    for (int n = 0; n < 512; ++n) {
        float sv = S[n * 512 + m];
        a0 += xs[0][n] * sv; a1 += xs[1][n] * sv;
        a2 += xs[2][n] * sv; a3 += xs[3][n] * sv;
    }
    Y[(bt0 + 0) * 512 + m] = a0; Y[(bt0 + 1) * 512 + m] = a1;
    Y[(bt0 + 2) * 512 + m] = a2; Y[(bt0 + 3) * 512 + m] = a3;
}

// ---------------- fused hg -> skip -> end1 -> end2 (E1 in registers, 2 e-passes) ----------------
// launch_bounds(256,2): budget = 512/2 = 256 unified regs/wave -> 2 waves/SIMD
// (2 blocks/CU). (256,1) let the allocator exceed 256 regs -> 1 wave/SIMD,
// occupancy 10.5% (round 4). (256,3) capped at 168 -> massive spill (rounds 2-3).
__launch_bounds__(256, 2)
__global__ void fused_k(const float* __restrict__ x, const float* __restrict__ Y,
                        const float* __restrict__ rs, const float* __restrict__ coef,
                        const float* __restrict__ gcn_b, const float* __restrict__ skip_b,
                        const float* __restrict__ end1_b,
                        const u16* __restrict__ W1, const u16* __restrict__ W2,
                        const u16* __restrict__ W3, float* __restrict__ part) {
    __shared__ __align__(16) u16 HG[64 * 64];    // [pix][o]   swizzled  (8 KB)
    __shared__ __align__(16) u16 SK[64 * 256];   // [pix][s]   swizzled  (32 KB; reused f32 for OUT partials)
    __shared__ float xs0[64], xs1[64], ys0[64], ys1[64], rsl[64];
    __shared__ float cf[384], gb[64], bsk[256], be1[512];

    const int tid = threadIdx.x;
    const int wid = tid >> 6;
    const int lane = tid & 63;
    const int lr = lane & 15;
    const int lh = lane >> 4;

    const int bid = blockIdx.x;
    const int ntile = bid & 7;
    const int btix = bid >> 3;       // b*31 + t
    const int t = btix % 31;
    const int b = btix / 31;
    const int n0 = ntile * 64;
    const int bt = b * 32 + t;

    if (tid < 64) {
        xs0[tid] = x[bt * 512 + n0 + tid];
        xs1[tid] = x[(bt + 1) * 512 + n0 + tid];
        ys0[tid] = Y[bt * 512 + n0 + tid];
        ys1[tid] = Y[(bt + 1) * 512 + n0 + tid];
        rsl[tid] = rs[n0 + tid];
        gb[tid]  = gcn_b[tid];
    }
    cf[tid] = coef[tid];
    if (tid < 128) cf[256 + tid] = coef[256 + tid];
    bsk[tid] = skip_b[tid];
    be1[tid] = end1_b[tid];
    be1[tid + 256] = end1_b[tid + 256];
    __syncthreads();

    // phase A: hg = tanh(fg) * sigmoid(g)  — fused: (e2f-1)*eg / ((e2f+1)*(1+eg))
#pragma unroll
    for (int k = 0; k < 16; ++k) {
        const int v = tid + k * 256;
        const int pix = v >> 6;
        const int o = v & 63;
        const float fgv = cf[o] * ys0[pix] + cf[64 + o] * ys1[pix]
                        + cf[128 + o] * rsl[pix] + gb[o];
        const float ggv = cf[192 + o] * xs0[pix] + cf[256 + o] * xs1[pix] + cf[320 + o];
        const float e2f = __expf(2.f * fgv);
        const float eg  = __expf(ggv);
        const float hv = ((e2f - 1.f) * eg) / ((e2f + 1.f) * (1.f + eg));
        HG[(pix << 6) | (o ^ ((pix & 7) << 3))] = f2b(hv);
    }
    __syncthreads();

    // GEMM1 (transposed): SKIP^T = skip_w x HG^T.  A=W1[s][o] (global), B=HG[pix][o] (LDS)
    {
        const int s0 = wid * 64;
        f32x4 acc[4][4];
#pragma unroll
        for (int i = 0; i < 4; ++i)
#pragma unroll
            for (int j = 0; j < 4; ++j) acc[i][j] = (f32x4){0.f, 0.f, 0.f, 0.f};
#pragma unroll
        for (int kk = 0; kk < 64; kk += 32) {
            const int kb = kk + lh * 8;
            bf16x8 a[4], bv[4];
#pragma unroll
            for (int i = 0; i < 4; ++i) {
                const int sr = s0 + i * 16 + lr;
                a[i] = *(const bf16x8*)(W1 + (sr << 6) + (kb ^ ((sr & 7) << 3)));
                const int pr = i * 16 + lr;
                bv[i] = *(const bf16x8*)(HG + (pr << 6) + (kb ^ ((pr & 7) << 3)));
            }
#pragma unroll
            for (int i = 0; i < 4; ++i)
#pragma unroll
                for (int j = 0; j < 4; ++j)
                    acc[i][j] = mfma16(a[i], bv[j], acc[i][j]);
        }
#pragma unroll
        for (int i = 0; i < 4; ++i) {
#pragma unroll
            for (int j = 0; j < 4; ++j) {
                const int pix = j * 16 + lr;
                const int xw = (pix & 7) << 3;
#pragma unroll
                for (int r = 0; r < 4; r += 2) {
                    const int s = s0 + i * 16 + lh * 4 + r;
                    const float v0 = fmaxf(acc[i][j][r] + bsk[s], 0.f);
                    const float v1 = fmaxf(acc[i][j][r + 1] + bsk[s + 1], 0.f);
                    *(u32*)(SK + (pix << 8) + (s ^ xw)) = (u32)f2b(v0) | ((u32)f2b(v1) << 16);
                }
            }
        }
    }
    __syncthreads();

    // GEMM2 (transposed) + GEMM3 fused in-register, TWO e-passes of 64 rows each.
    {
        const int e0 = wid * 128;
        f32x4 acc_out[4];
#pragma unroll
        for (int j = 0; j < 4; ++j) acc_out[j] = (f32x4){0.f, 0.f, 0.f, 0.f};

#pragma unroll
        for (int pass = 0; pass < 2; ++pass) {
            const int ep = e0 + pass * 64;
            f32x4 acc[4][4];
#pragma unroll
            for (int i = 0; i < 4; ++i)
#pragma unroll
                for (int j = 0; j < 4; ++j) acc[i][j] = (f32x4){0.f, 0.f, 0.f, 0.f};
#pragma unroll
            for (int kk = 0; kk < 256; kk += 32) {
                const int kb = kk + lh * 8;
                bf16x8 a[4], bv[4];
#pragma unroll
                for (int i = 0; i < 4; ++i) {
                    const int er = ep + i * 16 + lr;
                    a[i] = *(const bf16x8*)(W2 + (er << 8) + (kb ^ ((er & 7) << 3)));
                }
#pragma unroll
                for (int j = 0; j < 4; ++j) {
                    const int pr = j * 16 + lr;
                    bv[j] = *(const bf16x8*)(SK + (pr << 8) + (kb ^ ((pr & 7) << 3)));
                }
#pragma unroll
                for (int i = 0; i < 4; ++i)
#pragma unroll
                    for (int j = 0; j < 4; ++j)
                        acc[i][j] = mfma16(a[i], bv[j], acc[i][j]);
            }
            // bias + relu + pack to bf16 pairs (E1 values stay in registers)
            u32 pk[4][4][2];
#pragma unroll
            for (int i = 0; i < 4; ++i) {
#pragma unroll
                for (int j = 0; j < 4; ++j) {
                    const int eb = ep + i * 16 + lh * 4;
                    const float v0 = fmaxf(acc[i][j][0] + be1[eb + 0], 0.f);
                    const float v1 = fmaxf(acc[i][j][1] + be1[eb + 1], 0.f);
                    const float v2 = fmaxf(acc[i][j][2] + be1[eb + 2], 0.f);
                    const float v3 = fmaxf(acc[i][j][3] + be1[eb + 3], 0.f);
                    pk[i][j][0] = (u32)f2b(v0) | ((u32)f2b(v1) << 16);
                    pk[i][j][1] = (u32)f2b(v2) | ((u32)f2b(v3) << 16);
                }
            }
            // GEMM3 partial: W3 B-fragments for this pass's k'-range (64 wide = 2 chunks)
            bf16x8 bfr[2];
#pragma unroll
            for (int c = 0; c < 2; ++c)
                bfr[c] = *(const bf16x8*)(W3 + (lr << 9) + ep + c * 32 + lh * 8);
#pragma unroll
            for (int j = 0; j < 4; ++j) {
#pragma unroll
                for (int c = 0; c < 2; ++c) {
                    union { u32 w[4]; bf16x8 v; } af;
                    af.w[0] = pk[2 * c][j][0];
                    af.w[1] = pk[2 * c][j][1];
                    af.w[2] = pk[2 * c + 1][j][0];
                    af.w[3] = pk[2 * c + 1][j][1];
                    acc_out[j] = mfma16(af.v, bfr[c], acc_out[j]);
                }
            }
        }
        __syncthreads();   // all waves done reading SK (both passes); reuse as f32 scratch

        // stage per-wave K-split partials: SKf[wid][pix][p]
        float* SKf = (float*)SK;
#pragma unroll
        for (int j = 0; j < 4; ++j)
#pragma unroll
            for (int r = 0; r < 4; ++r)
                SKf[wid * 1024 + (j * 16 + lh * 4 + r) * 16 + lr] = acc_out[j][r];
    }
    __syncthreads();

    // cross-wave reduce + write part
    {
        const f32x4* Sv = (const f32x4*)SK;
        f32x4 sum = Sv[tid] + Sv[256 + tid] + Sv[512 + tid] + Sv[768 + tid];
        const int pix = tid >> 2;
        const int p0 = (tid & 3) << 2;
        if (p0 < 12) {
#pragma unroll
            for (int r = 0; r < 4; ++r)
                part[(btix * 12 + p0 + r) * 512 + n0 + pix] = sum[r];
        }
    }
}

// ---------------- mean over t + end2 bias ----------------
__global__ void reduce_k(const float* __restrict__ part, const float* __restrict__ end2_b,
                         float* __restrict__ out) {
    int i = blockIdx.x * 256 + threadIdx.x;
    if (i >= 8 * 12 * 512) return;
    int n = i & 511;
    int p = (i >> 9) % 12;
    int b = i / (12 * 512);
    const float* src = part + ((b * 31) * 12 + p) * 512 + n;
    float s = 0.f;
#pragma unroll
    for (int t = 0; t < 31; ++t) s += src[t * 12 * 512];
    out[i] = s * (1.f / 31.f) + end2_b[p];
}

extern "C" void kernel_launch(void* const* d_in, const int* in_sizes, int n_in,
                              void* d_out, int out_size, void* d_ws, size_t ws_size,
                              hipStream_t stream) {
    const float* x       = (const float*)d_in[0];
    const int*   ei      = (const int*)  d_in[1];
    const float* ew      = (const float*)d_in[2];
    const float* start_w = (const float*)d_in[3];
    const float* start_b = (const float*)d_in[4];
    const float* filt_w  = (const float*)d_in[5];
    const float* filt_b  = (const float*)d_in[6];
    const float* gate_w  = (const float*)d_in[7];
    const float* gate_b  = (const float*)d_in[8];
    const float* gcn_w   = (const float*)d_in[9];
    const float* gcn_b   = (const float*)d_in[10];
    const float* skip_w  = (const float*)d_in[13];
    const float* skip_b  = (const float*)d_in[14];
    const float* end1_w  = (const float*)d_in[15];
    const float* end1_b  = (const float*)d_in[16];
    const float* end2_w  = (const float*)d_in[17];
    const float* end2_b  = (const float*)d_in[18];
    float* out = (float*)d_out;

    char* ws = (char*)d_ws;
    float* S    = (float*)(ws);                 // 1,048,576 B
    float* deg  = (float*)(ws + 1048576);       // 2048 B
    float* rs   = (float*)(ws + 1050624);       // 2048 B   (memset with S+deg)
    float* dis  = (float*)(ws + 1052672);       // 2048 B
    float* Y    = (float*)(ws + 1054720);       // 524,288 B
    float* coef = (float*)(ws + 1579008);       // 1536 B
    u16*   W1   = (u16*)  (ws + 1580544);       // 32,768 B
    u16*   W2   = (u16*)  (ws + 1613312);       // 262,144 B
    u16*   W3   = (u16*)  (ws + 1875456);       // 16,384 B
    float* part = (float*)(ws + 1891840);       // 6,094,848 B

    hipMemsetAsync(S, 0, 1048576 + 4096, stream);    // S + deg + rs
    hipLaunchKernelGGL(deg_k,      dim3(34),  dim3(256), 0, stream, ei, ew, deg);
    hipLaunchKernelGGL(dis_coef_k, dim3(3),   dim3(256), 0, stream, deg, dis,
                       start_w, start_b, filt_w, filt_b, gate_w, gate_b, gcn_w, coef);
    hipLaunchKernelGGL(scat_wconv_k, dim3(546), dim3(256), 0, stream, ei, ew, dis,
                       skip_w, end1_w, end2_w, W1, W2, W3, S, rs);
    hipLaunchKernelGGL(y_k,    dim3(2, 64), dim3(256), 0, stream, x, S, Y);
    hipLaunchKernelGGL(fused_k, dim3(1984), dim3(256), 0, stream,
                       x, Y, rs, coef, gcn_b, skip_b, end1_b, W1, W2, W3, part);
    hipLaunchKernelGGL(reduce_k, dim3(192), dim3(256), 0, stream, part, end2_b, out);
}